// Round 1
// 58.766 us; speedup vs baseline: 1.1533x; 1.1533x over previous
//
#include <hip/hip_runtime.h>

#define BB 2048          // batches
#define TT 4096          // timesteps
#define LN2 0.69314718055994530942f

constexpr int clog2(int x) { int l = 0; while ((1 << l) < x) ++l; return l; }

// Record layout (12 planes, b-major within each plane: idx = b*NC + c):
//  0..8  : 3x3 matrix (row-major), value = stored * 2^shift
//  9     : shift (int bits)
//  10    : score (emit + within-range transition scores)
//  11    : packed tags: firstTag | (lastTag << 8)

// ---------------------------------------------------------------------------
// Pass 1: thread = (batch b, chunk c). LLC = NG*16 timesteps per chunk.
// REMAP vs previous version: c is in the LOW bits of the thread id, so the
// 64 lanes of a wave cover 64 consecutive chunks of the SAME batch -> every
// 16-step clause touches one contiguous 24KB logits span + 8KB tags span
// (previous mapping: 64 lanes spread over a 3MB span -> DRAM-page scatter,
// 1.5 TB/s). Workspace layout flipped to b-major so stores stay coalesced.
// ---------------------------------------------------------------------------
template<int NG>
__global__ __launch_bounds__(256, 4) void crf_pass1(
    const float* __restrict__ logits, const float* __restrict__ trans,
    const int* __restrict__ tags, float* __restrict__ ws)
{
    constexpr int LLC = NG * 16;
    constexpr int NC  = TT / LLC;
    constexpr int LOGNC = clog2(NC);
    constexpr size_t CB = (size_t)NC * BB;

    __shared__ float sTrans[9];
    __shared__ float sTrExp[9];
    int tid = threadIdx.x;
    if (tid < 9) {
        float tv = trans[tid];
        sTrans[tid] = tv;
        sTrExp[tid] = __expf(tv);
    }
    __syncthreads();

    int w = blockIdx.x * 256 + tid;
    int c = w & (NC - 1);            // lane-contiguous chunk index
    int b = w >> LOGNC;              // wave/block-uniform batch
    const bool first_chunk = (c == 0);

    float t00 = sTrExp[0], t01 = sTrExp[1], t02 = sTrExp[2];
    float t10 = sTrExp[3], t11 = sTrExp[4], t12 = sTrExp[5];
    float t20 = sTrExp[6], t21 = sTrExp[7], t22 = sTrExp[8];

    float a00 = 1.f, a01 = 0.f, a02 = 0.f;
    float a10 = 0.f, a11 = 1.f, a12 = 0.f;
    float a20 = 0.f, a21 = 0.f, a22 = 1.f;
    int   se = 0;
    float score = 0.f;
    int firstTag = 0, prev = 0;

    const float4* lp = (const float4*)(logits + ((size_t)b * TT + (size_t)c * LLC) * 3);
    const int4*   tp = (const int4*)(tags + (size_t)b * TT + (size_t)c * LLC);

#define MATSTEP(e0_, e1_, e2_) do {                                     \
    float x0 = __expf(e0_), x1 = __expf(e1_), x2 = __expf(e2_);         \
    float b0 = (a00*t00 + a01*t10 + a02*t20) * x0;                      \
    float b1 = (a00*t01 + a01*t11 + a02*t21) * x1;                      \
    float b2 = (a00*t02 + a01*t12 + a02*t22) * x2;                      \
    float b3 = (a10*t00 + a11*t10 + a12*t20) * x0;                      \
    float b4 = (a10*t01 + a11*t11 + a12*t21) * x1;                      \
    float b5 = (a10*t02 + a11*t12 + a12*t22) * x2;                      \
    float b6 = (a20*t00 + a21*t10 + a22*t20) * x0;                      \
    float b7 = (a20*t01 + a21*t11 + a22*t21) * x1;                      \
    float b8 = (a20*t02 + a21*t12 + a22*t22) * x2;                      \
    a00=b0; a01=b1; a02=b2; a10=b3; a11=b4; a12=b5; a20=b6; a21=b7; a22=b8; \
} while (0)

#define RENORM do {                                                     \
    float m = fmaxf(fmaxf(fmaxf(a00, a01), fmaxf(a02, a10)),            \
                    fmaxf(fmaxf(a11, a12), fmaxf(fmaxf(a20, a21), a22))); \
    int ef = (int)(__float_as_uint(m) >> 23);                           \
    float scf = __uint_as_float((unsigned)(254 - ef) << 23);            \
    se += ef - 127;                                                     \
    a00 *= scf; a01 *= scf; a02 *= scf;                                 \
    a10 *= scf; a11 *= scf; a12 *= scf;                                 \
    a20 *= scf; a21 *= scf; a22 *= scf;                                 \
} while (0)

#pragma unroll
    for (int g = 0; g < NG; ++g) {
        // ---- load one 16-step clause (all constant-index -> registers) ----
        float Lf[48];
        int   Ti[16];
#pragma unroll
        for (int i = 0; i < 12; ++i) {
            float4 t = lp[g * 12 + i];
            Lf[4*i+0] = t.x; Lf[4*i+1] = t.y; Lf[4*i+2] = t.z; Lf[4*i+3] = t.w;
        }
#pragma unroll
        for (int i = 0; i < 4; ++i) {
            int4 t = tp[g * 4 + i];
            Ti[4*i+0] = t.x; Ti[4*i+1] = t.y; Ti[4*i+2] = t.z; Ti[4*i+3] = t.w;
        }
        // ---- 16 steps ----
#pragma unroll
        for (int s = 0; s < 16; ++s) {
            float e0 = Lf[3*s+0], e1 = Lf[3*s+1], e2 = Lf[3*s+2];
            int tg = Ti[s];
            if (g == 0 && s == 0) {
                if (!first_chunk) MATSTEP(e0, e1, e2);
                firstTag = tg;
            } else {
                MATSTEP(e0, e1, e2);
                score += sTrans[prev * 3 + tg];
            }
            score += (tg == 0) ? e0 : ((tg == 1) ? e1 : e2);
            prev = tg;
            if ((s & 7) == 7) RENORM;
        }
    }

    size_t idx = (size_t)b * NC + c;          // b-major: lanes store contiguously
    ws[0*CB+idx] = a00; ws[1*CB+idx] = a01; ws[2*CB+idx] = a02;
    ws[3*CB+idx] = a10; ws[4*CB+idx] = a11; ws[5*CB+idx] = a12;
    ws[6*CB+idx] = a20; ws[7*CB+idx] = a21; ws[8*CB+idx] = a22;
    ((int*)ws)[9*CB+idx] = se;
    ws[10*CB+idx] = score;
    ((int*)ws)[11*CB+idx] = firstTag | (prev << 8);

#undef MATSTEP
#undef RENORM
}

// ---------------------------------------------------------------------------
// Pass 2a: thread = (batch b, super-chunk s). Folds 8 chunk records into one
// super-record. b-major layout: a lane's 8 records are CONTIGUOUS per plane,
// so each plane loads as 2x float4 (fully dense wave footprint).
// ---------------------------------------------------------------------------
__global__ __launch_bounds__(64) void crf_pass2a(
    const float* __restrict__ ws, float* __restrict__ ws2,
    const float* __restrict__ trans, int NC, int logNS)
{
    size_t CB  = (size_t)NC * BB;
    int NS = NC >> 3;
    size_t CB2 = (size_t)NS * BB;
    __shared__ float sTrans[9];
    if (threadIdx.x < 9) sTrans[threadIdx.x] = trans[threadIdx.x];
    __syncthreads();

    int u = blockIdx.x * 64 + threadIdx.x;
    int s = u & (NS - 1);            // lane-contiguous super-chunk
    int b = u >> logNS;

    size_t base = (size_t)b * NC + (size_t)s * 8;
    float M[12][8];
#pragma unroll
    for (int pl = 0; pl < 12; ++pl) {
        const float4* q = (const float4*)(ws + (size_t)pl * CB + base);
        float4 x = q[0], y = q[1];
        M[pl][0]=x.x; M[pl][1]=x.y; M[pl][2]=x.z; M[pl][3]=x.w;
        M[pl][4]=y.x; M[pl][5]=y.y; M[pl][6]=y.z; M[pl][7]=y.w;
    }

    float p00 = M[0][0], p01 = M[1][0], p02 = M[2][0];
    float p10 = M[3][0], p11 = M[4][0], p12 = M[5][0];
    float p20 = M[6][0], p21 = M[7][0], p22 = M[8][0];
    int   sh  = __float_as_int(M[9][0]);
    float score = M[10][0];
    int   pk  = __float_as_int(M[11][0]);
    int first0 = pk & 255, last = pk >> 8;

#pragma unroll
    for (int k = 1; k < 8; ++k) {
        float m00 = M[0][k], m01 = M[1][k], m02 = M[2][k];
        float m10 = M[3][k], m11 = M[4][k], m12 = M[5][k];
        float m20 = M[6][k], m21 = M[7][k], m22 = M[8][k];
        int   shm = __float_as_int(M[9][k]);
        float scm = M[10][k];
        int   pkm = __float_as_int(M[11][k]);

        float c00 = p00*m00 + p01*m10 + p02*m20;
        float c01 = p00*m01 + p01*m11 + p02*m21;
        float c02 = p00*m02 + p01*m12 + p02*m22;
        float c10 = p10*m00 + p11*m10 + p12*m20;
        float c11 = p10*m01 + p11*m11 + p12*m21;
        float c12 = p10*m02 + p11*m12 + p12*m22;
        float c20 = p20*m00 + p21*m10 + p22*m20;
        float c21 = p20*m01 + p21*m11 + p22*m21;
        float c22 = p20*m02 + p21*m12 + p22*m22;

        float mx = fmaxf(fmaxf(fmaxf(c00, c01), fmaxf(c02, c10)),
                         fmaxf(fmaxf(c11, c12), fmaxf(fmaxf(c20, c21), c22)));
        int ef = (int)(__float_as_uint(mx) >> 23);
        float scf = __uint_as_float((unsigned)(254 - ef) << 23);
        sh += shm + ef - 127;
        p00 = c00*scf; p01 = c01*scf; p02 = c02*scf;
        p10 = c10*scf; p11 = c11*scf; p12 = c12*scf;
        p20 = c20*scf; p21 = c21*scf; p22 = c22*scf;

        score += scm + sTrans[last * 3 + (pkm & 255)];
        last = pkm >> 8;
    }

    size_t o = (size_t)b * NS + s;   // b-major: lanes store contiguously
    ws2[0*CB2+o] = p00; ws2[1*CB2+o] = p01; ws2[2*CB2+o] = p02;
    ws2[3*CB2+o] = p10; ws2[4*CB2+o] = p11; ws2[5*CB2+o] = p12;
    ws2[6*CB2+o] = p20; ws2[7*CB2+o] = p21; ws2[8*CB2+o] = p22;
    ((int*)ws2)[9*CB2+o] = sh;
    ws2[10*CB2+o] = score;
    ((int*)ws2)[11*CB2+o] = first0 | (last << 8);
}

// ---------------------------------------------------------------------------
// Pass 2b: thread = batch. v = exp(logits[b,0,:]); fold NS super-records
// (b-major: a thread's records are contiguous -> float4 loads, 4 records
// per clause). nll = logz - score. Wave-reduce -> 32 partials.
// ---------------------------------------------------------------------------
template<int NS>
__global__ __launch_bounds__(64) void crf_pass2b(
    const float* __restrict__ logits, const float* __restrict__ ws2,
    const float* __restrict__ trans, float* __restrict__ partial)
{
    __shared__ float sTrans[9];
    if (threadIdx.x < 9) sTrans[threadIdx.x] = trans[threadIdx.x];
    __syncthreads();

    size_t CB2 = (size_t)NS * BB;
    int b = blockIdx.x * 64 + threadIdx.x;
    const float* lb = logits + (size_t)b * TT * 3;
    float v0 = __expf(lb[0]);
    float v1 = __expf(lb[1]);
    float v2 = __expf(lb[2]);
    int stot = 0; float score = 0.f; int last = 0;
    const size_t base = (size_t)b * NS;

#pragma unroll
    for (int sq = 0; sq < NS / 4; ++sq) {
        float Q[12][4];
#pragma unroll
        for (int pl = 0; pl < 12; ++pl) {
            float4 x = *(const float4*)(ws2 + (size_t)pl * CB2 + base + sq * 4);
            Q[pl][0] = x.x; Q[pl][1] = x.y; Q[pl][2] = x.z; Q[pl][3] = x.w;
        }
#pragma unroll
        for (int j = 0; j < 4; ++j) {
            int s = sq * 4 + j;
            float p00 = Q[0][j], p01 = Q[1][j], p02 = Q[2][j];
            float p10 = Q[3][j], p11 = Q[4][j], p12 = Q[5][j];
            float p20 = Q[6][j], p21 = Q[7][j], p22 = Q[8][j];
            int   sh  = __float_as_int(Q[9][j]);
            float sc  = Q[10][j];
            int   pk  = __float_as_int(Q[11][j]);

            score += sc;
            if (s > 0) score += sTrans[last * 3 + (pk & 255)];
            last = pk >> 8;

            float n0 = v0*p00 + v1*p10 + v2*p20;
            float n1 = v0*p01 + v1*p11 + v2*p21;
            float n2 = v0*p02 + v1*p12 + v2*p22;
            stot += sh;
            float mx = fmaxf(fmaxf(n0, n1), n2);
            int ef = (int)(__float_as_uint(mx) >> 23);
            float scf = __uint_as_float((unsigned)(254 - ef) << 23);
            stot += ef - 127;
            v0 = n0*scf; v1 = n1*scf; v2 = n2*scf;
        }
    }

    float logz = logf(v0 + v1 + v2) + (float)stot * LN2;
    float nll = logz - score;

    for (int off = 32; off > 0; off >>= 1) nll += __shfl_down(nll, off, 64);
    if (threadIdx.x == 0) partial[blockIdx.x] = nll;
}

__global__ __launch_bounds__(64) void crf_pass3(
    const float* __restrict__ partial, float* __restrict__ out)
{
    float v = (threadIdx.x < 32) ? partial[threadIdx.x] : 0.f;
    for (int off = 32; off > 0; off >>= 1) v += __shfl_down(v, off, 64);
    if (threadIdx.x == 0) out[0] = v;
}

extern "C" void kernel_launch(void* const* d_in, const int* in_sizes, int n_in,
                              void* d_out, int out_size, void* d_ws, size_t ws_size,
                              hipStream_t stream) {
    const float* logits = (const float*)d_in[0];
    const float* trans  = (const float*)d_in[1];
    const int*   tags   = (const int*)d_in[2];
    float* out = (float*)d_out;
    float* ws  = (float*)d_ws;

    auto need = [](int NC) -> size_t {
        return (size_t)12 * NC * BB * 4 + (size_t)12 * (NC/8) * BB * 4 + 256;
    };
    int NC;
    if      (ws_size >= need(128)) NC = 128;
    else if (ws_size >= need(64))  NC = 64;
    else                           NC = 32;

    float* ws2     = ws + (size_t)12 * NC * BB;
    float* partial = ws2 + (size_t)12 * (NC/8) * BB;
    int NS = NC / 8;
    int logNS = __builtin_ctz(NS);

    int blocks1 = NC * BB / 256;
    if (NC == 128)      crf_pass1<2><<<dim3(blocks1), dim3(256), 0, stream>>>(logits, trans, tags, ws);
    else if (NC == 64)  crf_pass1<4><<<dim3(blocks1), dim3(256), 0, stream>>>(logits, trans, tags, ws);
    else                crf_pass1<8><<<dim3(blocks1), dim3(256), 0, stream>>>(logits, trans, tags, ws);

    crf_pass2a<<<dim3(NS * BB / 64), dim3(64), 0, stream>>>(ws, ws2, trans, NC, logNS);

    if (NC == 128)      crf_pass2b<16><<<dim3(32), dim3(64), 0, stream>>>(logits, ws2, trans, partial);
    else if (NC == 64)  crf_pass2b<8><<<dim3(32), dim3(64), 0, stream>>>(logits, ws2, trans, partial);
    else                crf_pass2b<4><<<dim3(32), dim3(64), 0, stream>>>(logits, ws2, trans, partial);

    crf_pass3<<<dim3(1), dim3(64), 0, stream>>>(partial, out);
}